// Round 4
// baseline (302.687 us; speedup 1.0000x reference)
//
#include <hip/hip_runtime.h>
#include <hip/hip_cooperative_groups.h>
#include <math.h>

namespace cg = cooperative_groups;

#define PI_F 3.14159265358979323846f

// Problem: x (8,1,2048,2048) fp32 -> out (8,16,128,128) fp32
// 16x16 patches, D_in=256, D=16, 131072 patches (16384/batch).
// Pipeline is affine in the patch vector: out = A @ p + u, then GroupNorm.
// GroupNorm fused into cooperative main_k (grid.sync); out written once.

// Workspace float offsets
#define WS_AH    0      // A as fp16 [16][256] (2048 dwords)
#define WS_U     2048   // u[16]
#define WS_STATS 2112   // sum[64] @2112, sumsq[64] @2176

using half8   = __attribute__((ext_vector_type(8))) _Float16;
using floatx4 = __attribute__((ext_vector_type(4))) float;

__device__ __forceinline__ void gload_lds16(const void* g, void* l) {
    __builtin_amdgcn_global_load_lds(
        (const __attribute__((address_space(1))) uint32_t*)g,
        (__attribute__((address_space(3))) uint32_t*)l,
        16, 0, 0);
}

// ---------------------------------------------------------------------------
// prep: block e = output channel (16 blocks, 256 thr).
//   F[e][d] = sum_m cw[e][m] e^{+2pi i d m/16}
//   G[e][k] = sum_d (wr+i wi)[d][k] * F[e][d]
//   A[e][t] = (1/64) Re( sum_k G[e][k] e^{-2pi i k t/256} )  -> fp16 in ws
//   u[e]    = cb[e] + 0.25 Re( sum_d (br+i bi)[d] F[e][d] )
// Kernel boundary makes A/u/zeroed-stats coherent for main_k (all XCDs).
// ---------------------------------------------------------------------------
__global__ __launch_bounds__(256) void prep(
        const float* __restrict__ wr, const float* __restrict__ wi,
        const float* __restrict__ br, const float* __restrict__ bi,
        const float* __restrict__ cw, const float* __restrict__ cb,
        float* __restrict__ ws) {
    const int e = blockIdx.x;
    const int t = threadIdx.x;
    __shared__ float c16[16], s16[16], Fr[16], Fi[16];
    __shared__ float Gr[256], Gi[256], cosT[256], sinT[256];

    float ang = (2.0f * PI_F / 256.0f) * (float)t;
    cosT[t] = cosf(ang);
    sinT[t] = sinf(ang);
    if (t < 16) {
        float a = (2.0f * PI_F / 16.0f) * (float)t;
        c16[t] = cosf(a);
        s16[t] = sinf(a);
    }
    __syncthreads();

    if (t < 16) {                      // F[d=t]
        float fr = 0.f, fi = 0.f;
        #pragma unroll
        for (int m = 0; m < 16; ++m) {
            float c = cw[e * 16 + m];
            fr += c * c16[(t * m) & 15];
            fi += c * s16[(t * m) & 15];
        }
        Fr[t] = fr;
        Fi[t] = fi;
    }
    __syncthreads();

    {                                   // G[k=t]
        float gr = 0.f, gi = 0.f;
        #pragma unroll
        for (int d = 0; d < 16; ++d) {
            float wrv = wr[d * 256 + t];
            float wiv = wi[d * 256 + t];
            gr += wrv * Fr[d] - wiv * Fi[d];
            gi += wrv * Fi[d] + wiv * Fr[d];
        }
        Gr[t] = gr;
        Gi[t] = gi;
    }
    if (t == 0) {                       // u[e]
        float s = 0.f;
        #pragma unroll
        for (int d = 0; d < 16; ++d) s += br[d] * Fr[d] - bi[d] * Fi[d];
        ws[WS_U + e] = cb[e] + 0.25f * s;
    }
    __syncthreads();

    float acc = 0.f;
    for (int k = 0; k < 256; ++k) {
        int a = (k * t) & 255;
        acc += Gr[k] * cosT[a] + Gi[k] * sinT[a];
    }
    _Float16* Ah = (_Float16*)(ws + WS_AH);
    Ah[e * 256 + t] = (_Float16)(acc * (1.0f / 64.0f));

    if (e == 0 && t < 128) ws[WS_STATS + t] = 0.f;   // zero GN stats
}

// ---------------------------------------------------------------------------
// main (cooperative): 512 blocks x 256 thr; each block = 4 tiles of 64
// patches (one batch). x staged via global_load_lds half-tile granules
// (8 x 16B per wave), double-buffered, counted vmcnt (14-2s mid-loop,
// 6-2s last) -- never a full drain mid-pipeline. Per-lane global source is
// pre-swizzled so the linear LDS dest (base+lane*16) IS the read layout.
// A fp16 in 8x half8 regs. Outputs (16 floats/lane) held in regs across
// grid.sync(); GN stats via shfl tree + device-scope atomicAdd; after the
// sync, stats read with agent-scope atomic loads (cross-XCD safe) and out
// written once, normalized. Co-residency: 2 blocks/CU (LDS 64.25 KB).
// ---------------------------------------------------------------------------
__global__ __launch_bounds__(256) void main_k(const float* __restrict__ x,
                                              const float* __restrict__ ws,
                                              float* __restrict__ out,
                                              const float* __restrict__ gamma,
                                              const float* __restrict__ beta,
                                              float* __restrict__ stats) {
    __shared__ float x_sh[16384];        // 2 bufs x 4 waves x 2048 floats
    __shared__ float s_sum[4][8], s_ssq[4][8];
    const int t = threadIdx.x;

    const int w    = t >> 6;        // wave 0..3
    const int lane = t & 63;
    const int m    = lane & 15;     // patch-in-tile for A-frag; channel for C
    const int kg   = lane >> 4;     // k-group 0..3
    const int r_off = (kg >> 1);
    const int c_off = (kg & 1) << 3;

    // A fragments + bias first (oldest vmem ops -> compiler waits for them
    // without draining the x prefetch queue).
    const _Float16* Ah = (const _Float16*)(ws + WS_AH);
    half8 Areg[8];
    #pragma unroll
    for (int s = 0; s < 8; ++s)
        Areg[s] = *(const half8*)(Ah + m * 256 + s * 32 + kg * 8);
    const float u = ws[WS_U + m];

    // 4 tiles: T = blockIdx*4 + i, all in batch b; tb even -> pairs share ph
    const int T0  = blockIdx.x << 2;
    const int b   = T0 >> 8;
    const int tb0 = T0 & 255;
    const int ph01 = tb0 >> 1;           // tiles 0,1 ; tiles 2,3 at ph01+1
    const int cl   = (w * 16 + m) << 4;  // lane's patch column (floats)

    const float* xB  = x + ((size_t)b << 22);
    const float* xbA = xB + (size_t)(ph01 << 4) * 2048 + cl;
    const float* xbB = xbA + 1024;       // pw0 = 64
    const float* xbC = xbA + 32768;      // ph01 + 1
    const float* xbD = xbC + 1024;

    // granule G (half-tile): 8 loads/wave into buf (G&1)
#define ISSUE(G, XB) do {                                                  \
        float* lp_ = x_sh + ((G) & 1) * 8192 + w * 2048;                   \
        _Pragma("unroll")                                                  \
        for (int j = 0; j < 8; ++j) {                                      \
            const int sg_ = ((G) & 1) * 4 + (j >> 1);                      \
            const float* src_ = (XB) + (size_t)(2 * sg_ + r_off) * 2048    \
                                + c_off + 4 * (j & 1);                     \
            gload_lds16(src_, lp_ + j * 256);                              \
        }                                                                  \
    } while (0)

    const float* xw0 = x_sh + w * 2048 + lane * 4;
    const float* xw1 = xw0 + 8192;

#define STEP(BUFP, SL, SG, VMLIT) do {                                     \
        asm volatile("s_waitcnt vmcnt(" #VMLIT ")" ::: "memory");          \
        const float4 c0 = *(const float4*)((BUFP) + (SL) * 512);           \
        const float4 c1 = *(const float4*)((BUFP) + (SL) * 512 + 256);     \
        half8 a;                                                           \
        a[0] = (_Float16)c0.x; a[1] = (_Float16)c0.y;                      \
        a[2] = (_Float16)c0.z; a[3] = (_Float16)c0.w;                      \
        a[4] = (_Float16)c1.x; a[5] = (_Float16)c1.y;                      \
        a[6] = (_Float16)c1.z; a[7] = (_Float16)c1.w;                      \
        acc = __builtin_amdgcn_mfma_f32_16x16x32_f16(a, Areg[SG], acc,     \
                                                     0, 0, 0);             \
    } while (0)

#define CONSUME_LO(P)  STEP(P,0,0,14); STEP(P,1,1,12); STEP(P,2,2,10); STEP(P,3,3,8)
#define CONSUME_HI(P)  STEP(P,0,4,14); STEP(P,1,5,12); STEP(P,2,6,10); STEP(P,3,7,8)
#define CONSUME_HI_LAST(P) STEP(P,0,4,6); STEP(P,1,5,4); STEP(P,2,6,2); STEP(P,3,7,0)

    float4 vtA, vtB, vtC, vtD;
    float sv = 0.f, qv = 0.f;
#define FINISH_TILE(VT) do {                                               \
        (VT) = make_float4(acc[0] + u, acc[1] + u, acc[2] + u, acc[3] + u);\
        sv += (VT).x + (VT).y + (VT).z + (VT).w;                           \
        qv += (VT).x * (VT).x + (VT).y * (VT).y                            \
            + (VT).z * (VT).z + (VT).w * (VT).w;                           \
    } while (0)

    ISSUE(0, xbA); ISSUE(1, xbA);
    floatx4 acc = {0.f, 0.f, 0.f, 0.f};
    CONSUME_LO(xw0);
    ISSUE(2, xbB);
    CONSUME_HI(xw1);
    FINISH_TILE(vtA);
    ISSUE(3, xbB);
    acc = (floatx4){0.f, 0.f, 0.f, 0.f};
    CONSUME_LO(xw0);
    ISSUE(4, xbC);
    CONSUME_HI(xw1);
    FINISH_TILE(vtB);
    ISSUE(5, xbC);
    acc = (floatx4){0.f, 0.f, 0.f, 0.f};
    CONSUME_LO(xw0);
    ISSUE(6, xbD);
    CONSUME_HI(xw1);
    FINISH_TILE(vtC);
    ISSUE(7, xbD);
    acc = (floatx4){0.f, 0.f, 0.f, 0.f};
    CONSUME_LO(xw0);
    CONSUME_HI_LAST(xw1);
    FINISH_TILE(vtD);

#undef ISSUE
#undef STEP
#undef CONSUME_LO
#undef CONSUME_HI
#undef CONSUME_HI_LAST
#undef FINISH_TILE

    // GN stats: sum over kg (xor 16,32) -> per-channel; xor 1 -> group pair
    sv += __shfl_xor(sv, 16, 64);  qv += __shfl_xor(qv, 16, 64);
    sv += __shfl_xor(sv, 32, 64);  qv += __shfl_xor(qv, 32, 64);
    sv += __shfl_xor(sv, 1, 64);   qv += __shfl_xor(qv, 1, 64);
    if (kg == 0 && (m & 1) == 0) {
        s_sum[w][m >> 1] = sv;
        s_ssq[w][m >> 1] = qv;
    }
    __syncthreads();
    if (t < 8) {
        float S = s_sum[0][t] + s_sum[1][t] + s_sum[2][t] + s_sum[3][t];
        float Q = s_ssq[0][t] + s_ssq[1][t] + s_ssq[2][t] + s_ssq[3][t];
        atomicAdd(&stats[b * 8 + t],      S);     // device-scope RMW
        atomicAdd(&stats[64 + b * 8 + t], Q);
    }

    cg::this_grid().sync();

    // GN params (agent-scope loads: atomics live at the coherence point)
    const int g = m >> 1;
    float S = __hip_atomic_load(&stats[b * 8 + g],
                                __ATOMIC_RELAXED, __HIP_MEMORY_SCOPE_AGENT);
    float Q = __hip_atomic_load(&stats[64 + b * 8 + g],
                                __ATOMIC_RELAXED, __HIP_MEMORY_SCOPE_AGENT);
    const float inv_n = 1.0f / 32768.0f;
    float mean = S * inv_n;
    float var  = Q * inv_n - mean * mean;
    float rstd = rsqrtf(var + 1e-5f);
    float sc = rstd * gamma[m];
    float sh = beta[m] - mean * sc;

    float* ob = out + ((size_t)b << 18) + (size_t)m * 16384
                    + (size_t)(w * 16 + kg * 4);
    float* oA = ob + ((size_t)ph01 << 7);
    *(float4*)oA = make_float4(vtA.x * sc + sh, vtA.y * sc + sh,
                               vtA.z * sc + sh, vtA.w * sc + sh);
    *(float4*)(oA + 64) = make_float4(vtB.x * sc + sh, vtB.y * sc + sh,
                                      vtB.z * sc + sh, vtB.w * sc + sh);
    float* oC = oA + 128;
    *(float4*)oC = make_float4(vtC.x * sc + sh, vtC.y * sc + sh,
                               vtC.z * sc + sh, vtC.w * sc + sh);
    *(float4*)(oC + 64) = make_float4(vtD.x * sc + sh, vtD.y * sc + sh,
                                      vtD.z * sc + sh, vtD.w * sc + sh);
}

extern "C" void kernel_launch(void* const* d_in, const int* in_sizes, int n_in,
                              void* d_out, int out_size, void* d_ws, size_t ws_size,
                              hipStream_t stream) {
    const float* x  = (const float*)d_in[0];
    const float* wr = (const float*)d_in[1];
    const float* wi = (const float*)d_in[2];
    const float* br = (const float*)d_in[3];
    const float* bi = (const float*)d_in[4];
    const float* cw = (const float*)d_in[5];
    const float* cb = (const float*)d_in[6];
    const float* gm = (const float*)d_in[7];
    const float* bt = (const float*)d_in[8];
    float* out = (float*)d_out;
    float* ws  = (float*)d_ws;
    float* st  = ws + WS_STATS;

    prep<<<16, 256, 0, stream>>>(wr, wi, br, bi, cw, cb, ws);

    void* args[] = {(void*)&x, (void*)&ws, (void*)&out,
                    (void*)&gm, (void*)&bt, (void*)&st};
    hipLaunchCooperativeKernel((const void*)main_k, dim3(512), dim3(256),
                               args, 0, stream);
}

// Round 5
// 221.627 us; speedup vs baseline: 1.3658x; 1.3658x over previous
//
#include <hip/hip_runtime.h>
#include <math.h>

#define PI_F 3.14159265358979323846f

// Problem: x (8,1,2048,2048) fp32 -> out (8,16,128,128) fp32
// 16x16 patches, D_in=256, D=16, 131072 patches (16384/batch).
// Pipeline is affine in the patch vector: out = A @ p + u, then GroupNorm.
//
// main_k: every global load instruction is DENSE (64 lanes x 16B = one
// contiguous 1KB patch-row-group; full 64B-line utilization) -- prior
// variants loaded 16B-with-16B-gaps per instruction (~50% line density),
// which matched the observed ~2.7TB/s effective read ceiling. LDS stays
// linear (global_load_lds constraint); readers pick fragments at
// hr*256+q0*64+m*4 (bank-group m&7 -> 8 lanes/group = b128 floor).
// 32KB LDS -> 4 blocks/CU (2x round-3 TLP).

// Workspace float offsets
#define WS_AH    0      // A as fp16 [16][256] (2048 dwords)
#define WS_U     2048   // u[16]
#define WS_STATS 2112   // sum[64] @2112, sumsq[64] @2176

using half8   = __attribute__((ext_vector_type(8))) _Float16;
using floatx4 = __attribute__((ext_vector_type(4))) float;

__device__ __forceinline__ void gload_lds16(const void* g, void* l) {
    __builtin_amdgcn_global_load_lds(
        (const __attribute__((address_space(1))) uint32_t*)g,
        (__attribute__((address_space(3))) uint32_t*)l,
        16, 0, 0);
}

// ---------------------------------------------------------------------------
// prep: block e = output channel (16 blocks, 256 thr).
//   F[e][d] = sum_m cw[e][m] e^{+2pi i d m/16}
//   G[e][k] = sum_d (wr+i wi)[d][k] * F[e][d]
//   A[e][t] = (1/64) Re( sum_k G[e][k] e^{-2pi i k t/256} )  -> fp16 in ws
//   u[e]    = cb[e] + 0.25 Re( sum_d (br+i bi)[d] F[e][d] )
// ---------------------------------------------------------------------------
__global__ __launch_bounds__(256) void prep(
        const float* __restrict__ wr, const float* __restrict__ wi,
        const float* __restrict__ br, const float* __restrict__ bi,
        const float* __restrict__ cw, const float* __restrict__ cb,
        float* __restrict__ ws) {
    const int e = blockIdx.x;
    const int t = threadIdx.x;
    __shared__ float c16[16], s16[16], Fr[16], Fi[16];
    __shared__ float Gr[256], Gi[256], cosT[256], sinT[256];

    float ang = (2.0f * PI_F / 256.0f) * (float)t;
    cosT[t] = cosf(ang);
    sinT[t] = sinf(ang);
    if (t < 16) {
        float a = (2.0f * PI_F / 16.0f) * (float)t;
        c16[t] = cosf(a);
        s16[t] = sinf(a);
    }
    __syncthreads();

    if (t < 16) {                      // F[d=t]
        float fr = 0.f, fi = 0.f;
        #pragma unroll
        for (int m = 0; m < 16; ++m) {
            float c = cw[e * 16 + m];
            fr += c * c16[(t * m) & 15];
            fi += c * s16[(t * m) & 15];
        }
        Fr[t] = fr;
        Fi[t] = fi;
    }
    __syncthreads();

    {                                   // G[k=t]
        float gr = 0.f, gi = 0.f;
        #pragma unroll
        for (int d = 0; d < 16; ++d) {
            float wrv = wr[d * 256 + t];
            float wiv = wi[d * 256 + t];
            gr += wrv * Fr[d] - wiv * Fi[d];
            gi += wrv * Fi[d] + wiv * Fr[d];
        }
        Gr[t] = gr;
        Gi[t] = gi;
    }
    if (t == 0) {                       // u[e]
        float s = 0.f;
        #pragma unroll
        for (int d = 0; d < 16; ++d) s += br[d] * Fr[d] - bi[d] * Fi[d];
        ws[WS_U + e] = cb[e] + 0.25f * s;
    }
    __syncthreads();

    float acc = 0.f;
    for (int k = 0; k < 256; ++k) {
        int a = (k * t) & 255;
        acc += Gr[k] * cosT[a] + Gi[k] * sinT[a];
    }
    _Float16* Ah = (_Float16*)(ws + WS_AH);
    Ah[e * 256 + t] = (_Float16)(acc * (1.0f / 64.0f));

    if (e == 0 && t < 128) ws[WS_STATS + t] = 0.f;   // zero GN stats
}

// ---------------------------------------------------------------------------
// main: MFMA GEMM. Block = 256 thr = 4 waves = 64 consecutive patches;
// wave = 16 patches (one 16x16x32-f16 MFMA tile, K=256 over 8 steps).
// Per wave: 16 dense 1KB row-loads via global_load_lds, granule-pipelined
// 2 x 4KB (counted vmcnt 6/4/.../0). Row r of the wave's 16 patches is one
// contiguous 1KB: lane p sources byte (p&15)*64+(p>>4)*16, LDS dest linear.
// Reader lane(m,kg) step s: row R=2s+(kg>>1), fragment at q0*64+m*4 floats
// (q0=(kg&1)*2) -- identical values to prior rounds, bit-identical output.
// ---------------------------------------------------------------------------
__global__ __launch_bounds__(256) void main_k(const float* __restrict__ x,
                                              const float* __restrict__ ws,
                                              float* __restrict__ out,
                                              float* __restrict__ stats) {
    __shared__ float x_sh[8192];          // 4 waves x 2 bufs x 1024 floats
    __shared__ float s_sum[4][8], s_ssq[4][8];
    const int t = threadIdx.x;

    const int w    = t >> 6;       // wave -> tile 0..3
    const int lane = t & 63;
    const int m    = lane & 15;    // patch-in-tile for A-frag; channel for C
    const int kg   = lane >> 4;    // k-group 0..3

    // A fragments + bias first (oldest vmem -> drained by S0's vmcnt(6)).
    const _Float16* Ah = (const _Float16*)(ws + WS_AH);
    half8 Areg[8];
    #pragma unroll
    for (int s = 0; s < 8; ++s)
        Areg[s] = *(const half8*)(Ah + m * 256 + s * 32 + kg * 8);
    const float u = ws[WS_U + m];
    __builtin_amdgcn_sched_barrier(0);   // keep these before the x prefetches

    const int P0  = blockIdx.x << 6;   // 64 patches, same b, same ph
    const int b   = P0 >> 14;
    const int pi  = P0 & 16383;
    const int ph  = pi >> 7;
    const int pw0 = pi & 127;          // 0 or 64

    // wave's 16-patch row-group base; dense per-lane source offset
    const float* xw_g = x + ((size_t)b << 22)
                          + (size_t)(ph << 4) * 2048
                          + (size_t)((pw0 + w * 16) << 4);
    const int src_off = (lane & 15) * 16 + (lane >> 4) * 4;   // floats

    float* lw = x_sh + w * 2048;       // wave LDS base: 2 bufs x 1024 floats

    // granule G = rows 4G..4G+3 -> buf (G&1), slot r&3 (wave-uniform dest)
#define ISSUE4(G) do {                                                     \
        _Pragma("unroll")                                                  \
        for (int j = 0; j < 4; ++j) {                                      \
            const int r_ = 4 * (G) + j;                                    \
            gload_lds16(xw_g + (size_t)r_ * 2048 + src_off,                \
                        lw + ((G) & 1) * 1024 + j * 256);                  \
        }                                                                  \
    } while (0)

    // reader: per-lane constant offset; per-step compile-time offsets
    const float* rb = lw + (kg >> 1) * 256 + ((kg & 1) * 2) * 64 + m * 4;

    floatx4 acc = {0.f, 0.f, 0.f, 0.f};
#define STEP(S, VMLIT) do {                                                \
        asm volatile("s_waitcnt vmcnt(" #VMLIT ")" ::: "memory");          \
        const float* p_ = rb + (((S) >> 1) & 1) * 1024 + ((S) & 1) * 512;  \
        const float4 c0 = *(const float4*)p_;                              \
        const float4 c1 = *(const float4*)(p_ + 64);                       \
        half8 a;                                                           \
        a[0] = (_Float16)c0.x; a[1] = (_Float16)c0.y;                      \
        a[2] = (_Float16)c0.z; a[3] = (_Float16)c0.w;                      \
        a[4] = (_Float16)c1.x; a[5] = (_Float16)c1.y;                      \
        a[6] = (_Float16)c1.z; a[7] = (_Float16)c1.w;                      \
        acc = __builtin_amdgcn_mfma_f32_16x16x32_f16(a, Areg[S], acc,      \
                                                     0, 0, 0);             \
    } while (0)

    ISSUE4(0);          // rows 0-3  -> buf0
    ISSUE4(1);          // rows 4-7  -> buf1
    STEP(0, 6);         // rows 0,1   (drains Areg+u too)
    STEP(1, 4);         // rows 2,3
    ISSUE4(2);          // rows 8-11 -> buf0
    STEP(2, 6);         // rows 4,5
    STEP(3, 4);         // rows 6,7
    ISSUE4(3);          // rows 12-15 -> buf1
    STEP(4, 6);         // rows 8,9
    STEP(5, 4);         // rows 10,11
    STEP(6, 2);         // rows 12,13
    STEP(7, 0);         // rows 14,15
#undef ISSUE4
#undef STEP

    // C layout: col(ch)=m, row(patch-in-tile)=kg*4+r (consecutive pw).
    float v0 = acc[0] + u;
    float v1 = acc[1] + u;
    float v2 = acc[2] + u;
    float v3 = acc[3] + u;
    *(float4*)&out[((size_t)b << 18) + (size_t)m * 16384
                   + (size_t)(ph << 7) + (size_t)(pw0 + w * 16 + kg * 4)]
        = make_float4(v0, v1, v2, v3);

    // GN stats: sum over kg (xor 16,32) -> per-channel; xor 1 -> group pair
    float sv = v0 + v1 + v2 + v3;
    float qv = v0 * v0 + v1 * v1 + v2 * v2 + v3 * v3;
    sv += __shfl_xor(sv, 16, 64);  qv += __shfl_xor(qv, 16, 64);
    sv += __shfl_xor(sv, 32, 64);  qv += __shfl_xor(qv, 32, 64);
    sv += __shfl_xor(sv, 1, 64);   qv += __shfl_xor(qv, 1, 64);
    if (kg == 0 && (m & 1) == 0) {     // one lane per (wave, group) slot
        s_sum[w][m >> 1] = sv;
        s_ssq[w][m >> 1] = qv;
    }
    __syncthreads();
    if (t < 8) {
        float S = s_sum[0][t] + s_sum[1][t] + s_sum[2][t] + s_sum[3][t];
        float Q = s_ssq[0][t] + s_ssq[1][t] + s_ssq[2][t] + s_ssq[3][t];
        atomicAdd(&stats[b * 8 + t],      S);
        atomicAdd(&stats[64 + b * 8 + t], Q);
    }
}

// ---------------------------------------------------------------------------
// finalize: in-place GroupNorm on d_out using accumulated stats.
// ---------------------------------------------------------------------------
__global__ __launch_bounds__(256) void finalize(float* __restrict__ out,
                                                const float* __restrict__ stats,
                                                const float* __restrict__ gamma,
                                                const float* __restrict__ beta) {
    const int i    = blockIdx.x * 256 + threadIdx.x;  // float4 index
    const int flat = i << 2;
    const int b = flat >> 18;
    const int c = (flat >> 14) & 15;
    const int g = c >> 1;

    const float inv_n = 1.0f / 32768.0f;
    float mean = stats[b * 8 + g] * inv_n;
    float var  = stats[64 + b * 8 + g] * inv_n - mean * mean;
    float rstd = rsqrtf(var + 1e-5f);
    float sc = rstd * gamma[c];
    float sh = beta[c] - mean * sc;

    float4 vv = ((float4*)out)[i];
    vv.x = vv.x * sc + sh;
    vv.y = vv.y * sc + sh;
    vv.z = vv.z * sc + sh;
    vv.w = vv.w * sc + sh;
    ((float4*)out)[i] = vv;
}

extern "C" void kernel_launch(void* const* d_in, const int* in_sizes, int n_in,
                              void* d_out, int out_size, void* d_ws, size_t ws_size,
                              hipStream_t stream) {
    const float* x  = (const float*)d_in[0];
    const float* wr = (const float*)d_in[1];
    const float* wi = (const float*)d_in[2];
    const float* br = (const float*)d_in[3];
    const float* bi = (const float*)d_in[4];
    const float* cw = (const float*)d_in[5];
    const float* cb = (const float*)d_in[6];
    const float* gm = (const float*)d_in[7];
    const float* bt = (const float*)d_in[8];
    float* out = (float*)d_out;
    float* ws  = (float*)d_ws;

    prep<<<16, 256, 0, stream>>>(wr, wi, br, bi, cw, cb, ws);
    main_k<<<2048, 256, 0, stream>>>(x, ws, out, ws + WS_STATS);
    finalize<<<2048, 256, 0, stream>>>(out, ws + WS_STATS, gm, bt);
}